// Round 14
// baseline (24.572 us; speedup 1.0000x reference)
//
#include <hip/hip_runtime.h>
#include <hip/hip_fp16.h>

#define HW_  (1024 * 1024)   // 2^20
#define R_   8               // output rows per block
#define RS_  (R_ + 4)        // staged rows [r0-2, r0+9]
#define CW_  512             // output cols per block
#define SW_  528             // staged cols [c0-4, c0+524), mult of 16 (bank-neutral di)
#define SOFF (RS_ * SW_)     // 6336 half2: strip starts here
#define NB_  512             // threads per block
#define NG   (SOFF / 4)      // 1584 float4 staging groups

// Each si0 owns one output l: pi = (2*si0) mod 9, m0 = pi*2^20 + si0 = 9l.
// Taps q=0..8 at si0+q, node = tap q=5. col0 is loop-invariant per thread ->
// fast threads take ONE branch: compute 8 addresses, issue ALL 40 ds_reads
// into named registers (MLP), then compute 8 row-products + 4 logs.
template<int ODD>
__device__ __forceinline__ void ldtaps(const uint2* st64, const unsigned* st32,
                                       int b0, uint2& ta, uint2& tb, uint2& tc,
                                       uint2& td, unsigned& te) {
    if constexpr (!ODD) {
        ta = st64[b0 + 0]; tb = st64[b0 + 1]; tc = st64[b0 + 2]; td = st64[b0 + 3];
        te = st32[2 * b0 + 8];
    } else {
        ta = st64[b0 + 1]; tb = st64[b0 + 2]; tc = st64[b0 + 3]; td = st64[b0 + 4];
        te = st32[2 * b0 + 1];
    }
}

template<int ODD>
__device__ __forceinline__ float rowp(__half Th, uint2 ta, uint2 tb, uint2 tc,
                                      uint2 td, unsigned te) {
    unsigned h0, h1, h2, h3, h5, h6, h7, h8;
    if constexpr (!ODD) {
        h0 = ta.x; h1 = ta.y; h2 = tb.x; h3 = tb.y;
        h5 = tc.y; h6 = td.x; h7 = td.y; h8 = te;
    } else {
        h0 = te;   h1 = ta.x; h2 = ta.y; h3 = tb.x;
        h5 = tc.x; h6 = tc.y; h7 = td.x; h8 = td.y;
    }
    __half2 N = *reinterpret_cast<__half2*>(&h5);
    __half  nh = __low2half(N);
    float   ns = __half2float(__high2half(N));
    float c2 = 1.0f - ns, c1 = ns - c2;
    #define EDGE_(hw) ({ __half2 _t = *reinterpret_cast<__half2*>(&(hw)); \
        (__hle(__habs(__hsub(__low2half(_t), nh)), Th)) \
            ? fmaf(__half2float(__high2half(_t)), c1, c2) : 1.0f; })
    float f0 = EDGE_(h0);
    float f1 = EDGE_(h1);
    float f2 = EDGE_(h2);
    float f3 = EDGE_(h3);
    float f4 = fmaf(ns, c1, c2);       // self-edge q=5, |d|=0
    float f5 = EDGE_(h6);
    float f6 = EDGE_(h7);
    float f7 = EDGE_(h8);
    #undef EDGE_
    return ((f0 * f1) * (f2 * f3)) * ((f4 * f5) * (f6 * f7));
}

template<int ODD>
__device__ __forceinline__ float ploss_body(
        const __half2* st, const float* __restrict__ img, const float* __restrict__ lg,
        int r0, int col0, int colk, unsigned pi) {
    const float  T  = 0.21072103131565256f;  // -2*ln(0.9)
    const __half Th = __float2half(0.21072103f);
    const uint2*    st64 = reinterpret_cast<const uint2*>(st);
    const unsigned* st32 = reinterpret_cast<const unsigned*>(st);
    float acc = 0.0f;

    if (col0 < 1016) {
        // ---- whole-thread fast path: 8 addresses -> 40 ds_reads -> compute ----
        unsigned piq = pi;
        #define ADDR_(K) int b##K; { int i = (int)((piq * 171u) >> 9); \
            int j = (int)piq - 3 * i; \
            b##K = (((K) + 2 * i) * SW_ + (colk + 2 + 2 * j)) >> 1; \
            piq += 5u; if (piq >= 9u) piq -= 9u; }
        ADDR_(0) ADDR_(1) ADDR_(2) ADDR_(3) ADDR_(4) ADDR_(5) ADDR_(6) ADDR_(7)
        #undef ADDR_
        uint2 a0,b0v,c0v,d0v; unsigned e0;
        uint2 a1,b1v,c1v,d1v; unsigned e1;
        uint2 a2,b2v,c2v,d2v; unsigned e2;
        uint2 a3,b3v,c3v,d3v; unsigned e3;
        uint2 a4,b4v,c4v,d4v; unsigned e4;
        uint2 a5,b5v,c5v,d5v; unsigned e5;
        uint2 a6,b6v,c6v,d6v; unsigned e6;
        uint2 a7,b7v,c7v,d7v; unsigned e7;
        ldtaps<ODD>(st64, st32, b0, a0, b0v, c0v, d0v, e0);
        ldtaps<ODD>(st64, st32, b1, a1, b1v, c1v, d1v, e1);
        ldtaps<ODD>(st64, st32, b2, a2, b2v, c2v, d2v, e2);
        ldtaps<ODD>(st64, st32, b3, a3, b3v, c3v, d3v, e3);
        ldtaps<ODD>(st64, st32, b4, a4, b4v, c4v, d4v, e4);
        ldtaps<ODD>(st64, st32, b5, a5, b5v, c5v, d5v, e5);
        ldtaps<ODD>(st64, st32, b6, a6, b6v, c6v, d6v, e6);
        ldtaps<ODD>(st64, st32, b7, a7, b7v, c7v, d7v, e7);
        float p0 = rowp<ODD>(Th, a0, b0v, c0v, d0v, e0);
        float p1 = rowp<ODD>(Th, a1, b1v, c1v, d1v, e1);
        float p2 = rowp<ODD>(Th, a2, b2v, c2v, d2v, e2);
        float p3 = rowp<ODD>(Th, a3, b3v, c3v, d3v, e3);
        float p4 = rowp<ODD>(Th, a4, b4v, c4v, d4v, e4);
        float p5 = rowp<ODD>(Th, a5, b5v, c5v, d5v, e5);
        float p6 = rowp<ODD>(Th, a6, b6v, c6v, d6v, e6);
        float p7 = rowp<ODD>(Th, a7, b7v, c7v, d7v, e7);
        acc = -(__log2f(p0 * p1) + __log2f(p2 * p3)
              + __log2f(p4 * p5) + __log2f(p6 * p7));
        return acc;
    }

    // ---- rare columns (col0 >= 1016): per-row wrap / pi-crossing paths ----
    float pp = 1.0f;
    #pragma unroll
    for (int kk = 0; kk < R_; ++kk) {
        int rowk = kk;
        int i  = (int)((pi * 171u) >> 9);      // pi/3
        int j  = (int)pi - 3 * i;
        int di = 2 * i - 2, dj = 2 * j - 2;
        float p;
        if (r0 + rowk < 1023) {
            // ---- row-wrap path: taps q>=qs from the LDS strip ----
            int a0 = (rowk + 2 + di) * SW_ + (colk + 4 + dj);
            int qs = 1024 - col0;                               // 1..8
            int sbase = SOFF + (rowk + 2 + di) * 12 + (col0 - 1022 + dj);
            #define RDW_(q) __half22float2(st[(((q) < qs) ? a0 : sbase) + (q)])
            float2 t0 = RDW_(0);
            float2 t1 = RDW_(1);
            float2 t2 = RDW_(2);
            float2 t3 = RDW_(3);
            float2 t5 = RDW_(5);
            float2 t6 = RDW_(6);
            float2 t7 = RDW_(7);
            float2 t8 = RDW_(8);
            #undef RDW_
            float nimg = t5.x;
            float c1 = 2.0f * t5.y - 1.0f, c2 = 1.0f - t5.y;
            float f0 = (fabsf(nimg - t0.x) <= T) ? fmaf(t0.y, c1, c2) : 1.0f;
            float f1 = (fabsf(nimg - t1.x) <= T) ? fmaf(t1.y, c1, c2) : 1.0f;
            float f2 = (fabsf(nimg - t2.x) <= T) ? fmaf(t2.y, c1, c2) : 1.0f;
            float f3 = (fabsf(nimg - t3.x) <= T) ? fmaf(t3.y, c1, c2) : 1.0f;
            float f4 = fmaf(t5.y, c1, c2);
            float f5 = (fabsf(nimg - t6.x) <= T) ? fmaf(t6.y, c1, c2) : 1.0f;
            float f6 = (fabsf(nimg - t7.x) <= T) ? fmaf(t7.y, c1, c2) : 1.0f;
            float f7 = (fabsf(nimg - t8.x) <= T) ? fmaf(t8.y, c1, c2) : 1.0f;
            p = ((f0 * f1) * (f2 * f3)) * ((f4 * f5) * (f6 * f7));
        } else {
            // ---- pi-crossing sites (si0 >= 2^20-8): exact global path ----
            int m0 = (int)pi * HW_ + ((r0 + rowk) << 10) + col0;   // = 9l
            float nimg = 0.0f, nm = 0.0f;
            {
                int m = m0 + 5;
                int piq = m >> 20, siq = m & (HW_ - 1);
                int iq = (piq * 171) >> 9, jq = piq - 3 * iq;
                int rq = (siq >> 10) + 2 * iq - 2;
                int cq = (siq & 1023) + 2 * jq - 2;
                if ((unsigned)rq < 1024u && (unsigned)cq < 1024u) {
                    int off = (rq << 10) | cq;
                    nimg = img[off];
                    nm = 1.0f / (1.0f + __expf(-lg[off]));
                }
            }
            float c1 = 2.0f * nm - 1.0f, c2 = 1.0f - nm;
            p = 1.0f;
            #pragma unroll
            for (int q = 0; q < 9; ++q) {
                if (q == 4) continue;
                int m = m0 + q;
                int piq = m >> 20, siq = m & (HW_ - 1);
                int iq = (piq * 171) >> 9, jq = piq - 3 * iq;
                int rq = (siq >> 10) + 2 * iq - 2;
                int cq = (siq & 1023) + 2 * jq - 2;
                float eimg = 0.0f, em = 0.0f;
                if ((unsigned)rq < 1024u && (unsigned)cq < 1024u) {
                    int off = (rq << 10) | cq;
                    eimg = img[off];
                    em = 1.0f / (1.0f + __expf(-lg[off]));
                }
                p *= (fabsf(nimg - eimg) <= T) ? fmaf(em, c1, c2) : 1.0f;
            }
        }
        if (kk & 1) acc -= __log2f(pp * p);    // one log per row-pair (16 factors)
        else        pp = p;
        pi += 5u;                              // +2*1024 mod 9
        if (pi >= 9u) pi -= 9u;
    }
    return acc;
}

__global__ __launch_bounds__(NB_, 4) void ploss14(
        const float* __restrict__ logits_,
        const float* __restrict__ image_,
        float* __restrict__ part, int nwg, float scale) {
    __shared__ __half2 st[SOFF + 144];   // 25.9 KB

    // bijective XCD-chunked swizzle (nwg % 8 == 0)
    int bid = blockIdx.x;
    int wg  = (bid & 7) * (nwg >> 3) + (bid >> 3);

    int c   = wg >> 8;                 // 256 blocks per class
    int rem = wg & 255;
    int r0  = (rem >> 1) * R_;
    int c0  = (rem & 1) * CW_;
    const float* __restrict__ img = image_  + (size_t)c * HW_;
    const float* __restrict__ lg  = logits_ + (size_t)c * HW_;
    int tid = threadIdx.x;

    // ---- stage main tile: float4 groups, no partial vectors by construction ----
    for (unsigned g = tid; g < NG; g += NB_) {
        unsigned rr = g / 132u;            // 132 groups per row
        int gc  = (int)(g - rr * 132u);
        int row = r0 - 2 + (int)rr;
        int col4 = c0 - 4 + (gc << 2);
        float4 w;
        __half2* wh = reinterpret_cast<__half2*>(&w);
        if ((unsigned)row < 1024u && (unsigned)col4 < 1021u) {
            const float4 a = *reinterpret_cast<const float4*>(img + ((size_t)row << 10) + col4);
            const float4 b = *reinterpret_cast<const float4*>(lg  + ((size_t)row << 10) + col4);
            wh[0] = __floats2half2_rn(a.x, 1.0f / (1.0f + __expf(-b.x)));
            wh[1] = __floats2half2_rn(a.y, 1.0f / (1.0f + __expf(-b.y)));
            wh[2] = __floats2half2_rn(a.z, 1.0f / (1.0f + __expf(-b.z)));
            wh[3] = __floats2half2_rn(a.w, 1.0f / (1.0f + __expf(-b.w)));
        } else {
            w = make_float4(0.0f, 0.0f, 0.0f, 0.0f);
        }
        reinterpret_cast<float4*>(st)[g] = w;
    }
    // ---- strip (right tiles only): 12 rows [r0-1, r0+10], cols [-2, 10) ----
    if (c0 != 0 && tid < 144) {
        unsigned rr = (unsigned)tid / 12u;
        int cc = tid - (int)rr * 12;
        int row = r0 - 1 + (int)rr, col = cc - 2;
        float iv = 0.0f, mv = 0.0f;
        if ((unsigned)row < 1024u && (unsigned)col < 1024u) {
            int off = (row << 10) | col;
            iv = img[off];
            mv = 1.0f / (1.0f + __expf(-lg[off]));
        }
        st[SOFF + tid] = __floats2half2_rn(iv, mv);
    }
    __syncthreads();

    // thread->site remap: waves 0-3 even cols, waves 4-7 odd cols (uniform parity)
    int tsub  = tid & 255;
    int colk0 = (tsub << 1) | (tid >> 8);
    int col0  = c0 + colk0;                    // loop-invariant per thread
    unsigned pi0 = (2u * (unsigned)((r0 << 10) + col0)) % 9u;

    float acc;
    if (tid < 256) acc = ploss_body<0>(st, img, lg, r0, col0, colk0, pi0);
    else           acc = ploss_body<1>(st, img, lg, r0, col0, colk0, pi0);
    acc *= scale;                              // scale includes ln2

    // wave shuffle reduce -> LDS -> ONE plain store per block (no atomics)
    #pragma unroll
    for (int o = 32; o > 0; o >>= 1) acc += __shfl_down(acc, o, 64);
    __shared__ float sm[8];
    int lane = tid & 63, wid = tid >> 6;
    if (lane == 0) sm[wid] = acc;
    __syncthreads();
    if (tid == 0) {
        float s = 0.0f;
        #pragma unroll
        for (int w2 = 0; w2 < 8; ++w2) s += sm[w2];
        part[wg] = s;
    }
}

// single-block final reduce of nwg partials
__global__ __launch_bounds__(256) void preduce(
        const float* __restrict__ part, float* __restrict__ out, int n) {
    float acc = 0.0f;
    for (int i = threadIdx.x; i < n; i += 256) acc += part[i];
    #pragma unroll
    for (int o = 32; o > 0; o >>= 1) acc += __shfl_down(acc, o, 64);
    __shared__ float sm[4];
    int lane = threadIdx.x & 63, wid = threadIdx.x >> 6;
    if (lane == 0) sm[wid] = acc;
    __syncthreads();
    if (threadIdx.x == 0) out[0] = sm[0] + sm[1] + sm[2] + sm[3];
}

extern "C" void kernel_launch(void* const* d_in, const int* in_sizes, int n_in,
                              void* d_out, int out_size, void* d_ws, size_t ws_size,
                              hipStream_t stream) {
    const float* logits = (const float*)d_in[0];  // inputs (N,1,H,W) fp32
    const float* image  = (const float*)d_in[1];  // image  (N,1,H,W) fp32
    float* out  = (float*)d_out;
    float* part = (float*)d_ws;                   // nwg floats of scratch

    int nc  = in_sizes[0] / HW_;                          // 4
    int nwg = nc * (1024 / R_) * (1024 / CW_);            // 1024
    // acc is in log2 units -> fold ln2 into the scale
    float scale = 0.69314718055994531f / ((float)nc * (float)HW_);

    ploss14<<<nwg, NB_, 0, stream>>>(logits, image, part, nwg, scale);
    preduce<<<1, 256, 0, stream>>>(part, out, nwg);
}